// Round 2
// baseline (160.805 us; speedup 1.0000x reference)
//
#include <hip/hip_runtime.h>

// ExactAttention: block-diagonal masked softmax(Q K^T / sqrt(d)) @ V
// N=12288, D=128, 32 sorted batch segments. Global-max/EPS deviation ~1e-8
// relative -> plain masked softmax (no max subtraction, partials are linear).
//
// R2 structure: WG(256)=4 waves owns 16 query rows; waves split the key range
// in 32-key chunks (stride-4 over 128-key superblocks). K frags direct
// global->reg; V^T staged cooperatively in LDS; cross-wave O/l reduction in
// LDS epilogue. 768 WGs -> all co-resident (~12 waves/CU).

#define NN 12288
#define DD 128
#define BROWS 16
#define SB 128         // keys per superblock = 4 waves * 32
#define VT_LD 132      // Vt row stride (shorts): stride 264B -> 4-way banks
#define PS_LD 40       // P row stride (shorts)

typedef __attribute__((ext_vector_type(8))) short short8;
typedef __attribute__((ext_vector_type(4))) float float4v;

__device__ __forceinline__ short f2bf(float f) {
  // round-to-nearest-even fp32 -> bf16 (inputs finite)
  unsigned u = __builtin_bit_cast(unsigned, f);
  unsigned r = (u + 0x7FFFu + ((u >> 16) & 1u)) >> 16;
  return (short)r;
}

__device__ __forceinline__ short8 ldK_bf16(const float* p) {
  float4v f0 = *(const float4v*)p;
  float4v f1 = *(const float4v*)(p + 4);
  short8 s;
  s[0] = f2bf(f0[0]); s[1] = f2bf(f0[1]); s[2] = f2bf(f0[2]); s[3] = f2bf(f0[3]);
  s[4] = f2bf(f1[0]); s[5] = f2bf(f1[1]); s[6] = f2bf(f1[2]); s[7] = f2bf(f1[3]);
  return s;
}

__global__ __launch_bounds__(256) void attn_kernel(
    const float* __restrict__ Q, const float* __restrict__ K,
    const float* __restrict__ V, const int* __restrict__ seg,
    float* __restrict__ out) {
  __shared__ __align__(16) short Vt[DD * VT_LD];     // 33792 B, V^T tile
  __shared__ __align__(16) short Ps[4][16 * PS_LD];  // 5120 B, per-wave P
  __shared__ float Ls[4][16];                        // cross-wave l partials

  const int tid  = threadIdx.x;
  const int wave = tid >> 6;
  const int lane = tid & 63;
  const int c    = lane & 15;
  const int quad = lane >> 4;

  const int i0 = blockIdx.x * BROWS;

  // --- key range covered by this WG's 16 rows (segments are sorted) ---
  const int segFirst = seg[i0];
  const int segLast  = seg[i0 + BROWS - 1];
  int lo = 0, hb = NN;
  while (lo < hb) { int mid = (lo + hb) >> 1; if (seg[mid] < segFirst) lo = mid + 1; else hb = mid; }
  int hi = lo, hb2 = NN;
  while (hi < hb2) { int mid = (hi + hb2) >> 1; if (seg[mid] <= segLast) hi = mid + 1; else hb2 = mid; }

  // --- resident Q A-fragments: lane holds Q[i0+c][kc*32 + quad*8 .. +7] ---
  short8 qf[4];
  {
    const float* qrow = Q + (size_t)(i0 + c) * DD + quad * 8;
#pragma unroll
    for (int kc = 0; kc < 4; ++kc) qf[kc] = ldK_bf16(qrow + kc * 32);
  }

  int seg_r[4];
#pragma unroll
  for (int r = 0; r < 4; ++r) seg_r[r] = seg[i0 + quad * 4 + r];

  float4v acc[8];
#pragma unroll
  for (int n = 0; n < 8; ++n) acc[n] = (float4v){0.f, 0.f, 0.f, 0.f};
  float l_part[4] = {0.f, 0.f, 0.f, 0.f};

  const float scale = 0.08838834764831845f; // 1/sqrt(128)

  for (int sbase = lo; sbase < hi; sbase += SB) {
    __syncthreads();  // previous superblock's Vt reads complete

    // --- stage V^T tile: 128 keys x 128 d, bf16, transposed ---
    {
      const int d = tid & 127, h = tid >> 7;  // h in {0,1}
      const float* vp = V + d;
      short* dst = &Vt[d * VT_LD + h * 64];
      const int kbase = sbase + h * 64;
#pragma unroll
      for (int b = 0; b < 8; ++b) {
        short8 s;
#pragma unroll
        for (int j = 0; j < 8; ++j) {
          int kk = kbase + b * 8 + j; if (kk > NN - 1) kk = NN - 1;
          s[j] = f2bf(vp[(size_t)kk * DD]);
        }
        *(short8*)(dst + b * 8) = s;
      }
    }
    __syncthreads();

    const int j0 = sbase + wave * 32;  // this wave's 32-key chunk
    if (j0 < hi) {
      // --- S = Q K^T, K B-frags direct from global ---
      float4v s0 = (float4v){0.f, 0.f, 0.f, 0.f};
      float4v s1 = (float4v){0.f, 0.f, 0.f, 0.f};
      int ra = j0 + c;      if (ra > NN - 1) ra = NN - 1;
      int rb = j0 + 16 + c; if (rb > NN - 1) rb = NN - 1;
      const float* ka = K + (size_t)ra * DD + quad * 8;
      const float* kb = K + (size_t)rb * DD + quad * 8;
#pragma unroll
      for (int kc = 0; kc < 4; ++kc) {
        short8 b0 = ldK_bf16(ka + kc * 32);
        short8 b1 = ldK_bf16(kb + kc * 32);
        s0 = __builtin_amdgcn_mfma_f32_16x16x32_bf16(qf[kc], b0, s0, 0, 0, 0);
        s1 = __builtin_amdgcn_mfma_f32_16x16x32_bf16(qf[kc], b1, s1, 0, 0, 0);
      }

      // --- mask + exp, row-sum partials, P -> LDS (A-layout feed) ---
      int ja = j0 + c, jb = ja + 16;
      int sa = seg[ja < NN ? ja : NN - 1];
      int sb_ = seg[jb < NN ? jb : NN - 1];
      bool va = ja < hi, vb = jb < hi;
      short* prow = &Ps[wave][0];
#pragma unroll
      for (int r = 0; r < 4; ++r) {
        float pa = (va && sa == seg_r[r]) ? __expf(s0[r] * scale) : 0.f;
        float pb = (vb && sb_ == seg_r[r]) ? __expf(s1[r] * scale) : 0.f;
        l_part[r] += pa + pb;
        int row = quad * 4 + r;
        prow[row * PS_LD + c]      = f2bf(pa);
        prow[row * PS_LD + 16 + c] = f2bf(pb);
      }
      __asm__ volatile("s_waitcnt lgkmcnt(0)" ::: "memory");  // in-wave w->r

      // --- O += P V ---
      short8 pf = *(const short8*)&Ps[wave][c * PS_LD + quad * 8];
      const int koff = wave * 32 + quad * 8;
#pragma unroll
      for (int n = 0; n < 8; ++n) {
        short8 vf = *(const short8*)&Vt[(n * 16 + c) * VT_LD + koff];
        acc[n] = __builtin_amdgcn_mfma_f32_16x16x32_bf16(pf, vf, acc[n], 0, 0, 0);
      }
    }
  }

  // --- in-wave l reduction over the 16 key-cols (lanes sharing a quad) ---
  float lrow[4];
#pragma unroll
  for (int r = 0; r < 4; ++r) {
    float l = l_part[r];
    l += __shfl_xor(l, 1, 64);
    l += __shfl_xor(l, 2, 64);
    l += __shfl_xor(l, 4, 64);
    l += __shfl_xor(l, 8, 64);
    lrow[r] = l;
  }

  // --- cross-wave reduction of O and l through LDS, normalize, store ---
  __syncthreads();  // all Vt reads done; reuse as fp32 scratch
  float* Osc = (float*)&Vt[0];  // [4 waves][16 rows][128 cols] = 32768 B
#pragma unroll
  for (int n = 0; n < 8; ++n) {
#pragma unroll
    for (int r = 0; r < 4; ++r) {
      Osc[wave * 2048 + (quad * 4 + r) * 128 + n * 16 + c] = acc[n][r];
    }
  }
  if (c == 0) {
#pragma unroll
    for (int r = 0; r < 4; ++r) Ls[wave][quad * 4 + r] = lrow[r];
  }
  __syncthreads();

#pragma unroll
  for (int k = 0; k < 8; ++k) {
    int e = k * 256 + tid;          // element in [16][128]
    int row = e >> 7, col = e & 127;
    float o = Osc[e] + Osc[2048 + e] + Osc[4096 + e] + Osc[6144 + e];
    float l = Ls[0][row] + Ls[1][row] + Ls[2][row] + Ls[3][row];
    out[(size_t)(i0 + row) * DD + col] = o / (l + 1e-8f);
  }
}

extern "C" void kernel_launch(void* const* d_in, const int* in_sizes, int n_in,
                              void* d_out, int out_size, void* d_ws, size_t ws_size,
                              hipStream_t stream) {
  const float* Q = (const float*)d_in[0];
  const float* K = (const float*)d_in[1];
  const float* V = (const float*)d_in[2];
  // d_in[3] = num_batch (scalar, unused: mask derived from batch_seg)
  const int* seg = (const int*)d_in[4];
  float* out = (float*)d_out;
  attn_kernel<<<NN / BROWS, 256, 0, stream>>>(Q, K, V, seg, out);
}

// Round 3
// 118.909 us; speedup vs baseline: 1.3523x; 1.3523x over previous
//
#include <hip/hip_runtime.h>

// ExactAttention: block-diagonal masked softmax(Q K^T / sqrt(d)) @ V
// N=12288, D=128, 32 sorted batch segments, fp32 in/out.
// Global-max/EPS deviation ~1e-8 relative -> plain masked softmax.
//
// R3: prep kernel materializes bf16 K [N][D], bf16 V^T [D][N], and segment
// starts[] in d_ws. Attention kernel then needs NO in-loop LDS staging and NO
// in-loop barriers: MFMA B-frags for both QK^T and PV are direct 16B
// global->register loads. WG = 16 rows, 4 waves 4-way-split the key range,
// one LDS reduction at the end. Segment-compare mask makes foreign/tail keys
// exactly zero, so aligning lo down to 32 is free and keeps loads 16B-aligned.

#define NN 12288
#define DD 128
#define NB 32
#define PS_LD 40

typedef __attribute__((ext_vector_type(8))) short short8;
typedef __attribute__((ext_vector_type(4))) float float4v;

__device__ __forceinline__ short f2bf(float f) {
  // round-to-nearest-even fp32 -> bf16 (inputs finite)
  unsigned u = __builtin_bit_cast(unsigned, f);
  return (short)((u + 0x7FFFu + ((u >> 16) & 1u)) >> 16);
}

// ---------- prep: Kb = bf16(K); Vtb = bf16(V)^T; starts[b] = seg lower bound
__global__ __launch_bounds__(256) void prep_kernel(
    const float* __restrict__ K, const float* __restrict__ V,
    const int* __restrict__ seg,
    short* __restrict__ Kb, short* __restrict__ Vtb, int* __restrict__ starts) {
  const int tid = threadIdx.x;
  const int b = blockIdx.x;
  if (b < 768) {
    // K -> bf16, coalesced, 2048 elems/block
    const size_t base = (size_t)b * 2048 + (size_t)tid * 8;
    float4v f0 = *(const float4v*)(K + base);
    float4v f1 = *(const float4v*)(K + base + 4);
    short8 s;
    s[0] = f2bf(f0[0]); s[1] = f2bf(f0[1]); s[2] = f2bf(f0[2]); s[3] = f2bf(f0[3]);
    s[4] = f2bf(f1[0]); s[5] = f2bf(f1[1]); s[6] = f2bf(f1[2]); s[7] = f2bf(f1[3]);
    *(short8*)(Kb + base) = s;
  } else if (b < 864) {
    // V 128-key x 128-d tile transpose through LDS (one-time cost)
    __shared__ __align__(16) short Ts[DD * 136];
    const int kt = (b - 768) * 128;
#pragma unroll
    for (int rep = 0; rep < 16; ++rep) {
      int v = rep * 256 + tid;            // [128 keys][32 float4-cols]
      int key = v >> 5, c4 = (v & 31) * 4;
      float4v f = *(const float4v*)(V + (size_t)(kt + key) * DD + c4);
      Ts[(c4 + 0) * 136 + key] = f2bf(f[0]);
      Ts[(c4 + 1) * 136 + key] = f2bf(f[1]);
      Ts[(c4 + 2) * 136 + key] = f2bf(f[2]);
      Ts[(c4 + 3) * 136 + key] = f2bf(f[3]);
    }
    __syncthreads();
    const int c16 = (tid & 15) * 8;
#pragma unroll
    for (int rep = 0; rep < 8; ++rep) {
      int d = rep * 16 + (tid >> 4);
      short8 s = *(const short8*)&Ts[d * 136 + c16];
      *(short8*)(Vtb + (size_t)d * NN + kt + c16) = s;
    }
  } else {
    // starts[b] = first i with seg[i] >= b, b in [0, NB]
    for (int i = tid; i < NN; i += 256) {
      int s = seg[i];
      int sp = (i == 0) ? -1 : seg[i - 1];
      for (int bb = sp + 1; bb <= s; ++bb) starts[bb] = i;
      if (i == NN - 1)
        for (int bb = s + 1; bb <= NB; ++bb) starts[bb] = NN;
    }
  }
}

// ---------- attention: no in-loop LDS staging, no in-loop barriers
__global__ __launch_bounds__(256, 3) void attn_kernel(
    const float* __restrict__ Q, const short* __restrict__ Kb,
    const short* __restrict__ Vtb, const int* __restrict__ seg,
    const int* __restrict__ starts, float* __restrict__ out) {
  __shared__ __align__(16) short Ps[4][16 * PS_LD];  // per-wave P round-trip
  __shared__ __align__(16) float Osc[4][16 * DD];    // cross-wave O partials
  __shared__ float Ls[4][16];                        // cross-wave l partials

  const int tid = threadIdx.x;
  const int wave = tid >> 6;
  const int lane = tid & 63;
  const int c = lane & 15;
  const int quad = lane >> 4;

  // XCD swizzle: row-groups sharing a segment (hence K/V) land on one XCD
  const int bid = blockIdx.x;
  const int rg = (bid & 7) * 96 + (bid >> 3);
  const int i0 = rg * 16;

  const int lo = starts[seg[i0]] & ~31;      // align down: foreign keys masked
  const int hi = starts[seg[i0 + 15] + 1];

  // resident Q A-frags: lane holds Q[i0+c][kc*32 + quad*8 .. +7]
  short8 qf[4];
  {
    const float* qrow = Q + (size_t)(i0 + c) * DD + quad * 8;
#pragma unroll
    for (int kc = 0; kc < 4; ++kc) {
      float4v f0 = *(const float4v*)(qrow + kc * 32);
      float4v f1 = *(const float4v*)(qrow + kc * 32 + 4);
      short8 s;
      s[0] = f2bf(f0[0]); s[1] = f2bf(f0[1]); s[2] = f2bf(f0[2]); s[3] = f2bf(f0[3]);
      s[4] = f2bf(f1[0]); s[5] = f2bf(f1[1]); s[6] = f2bf(f1[2]); s[7] = f2bf(f1[3]);
      qf[kc] = s;
    }
  }

  int seg_r[4];
#pragma unroll
  for (int r = 0; r < 4; ++r) seg_r[r] = seg[i0 + quad * 4 + r];

  float4v acc[8];
#pragma unroll
  for (int n = 0; n < 8; ++n) acc[n] = (float4v){0.f, 0.f, 0.f, 0.f};
  float l_part[4] = {0.f, 0.f, 0.f, 0.f};

  const float scale = 0.08838834764831845f;  // 1/sqrt(128)

  for (int j0 = lo + wave * 32; j0 < hi; j0 += 128) {
    // V^T B-frags for this chunk: issue the 8 loads first (16B, aligned)
    short8 vf[8];
    {
      const short* vbase = Vtb + (size_t)c * NN + j0 + quad * 8;
#pragma unroll
      for (int n = 0; n < 8; ++n)
        vf[n] = *(const short8*)(vbase + (size_t)n * 16 * NN);
    }
    // K B-frags direct from bf16 global; S = Q K^T (16q x 32k)
    float4v s0 = (float4v){0.f, 0.f, 0.f, 0.f};
    float4v s1 = (float4v){0.f, 0.f, 0.f, 0.f};
    {
      const short* ka = Kb + (size_t)(j0 + c) * DD + quad * 8;
      const short* kb = ka + 16 * DD;
#pragma unroll
      for (int kc = 0; kc < 4; ++kc) {
        short8 b0 = *(const short8*)(ka + kc * 32);
        short8 b1 = *(const short8*)(kb + kc * 32);
        s0 = __builtin_amdgcn_mfma_f32_16x16x32_bf16(qf[kc], b0, s0, 0, 0, 0);
        s1 = __builtin_amdgcn_mfma_f32_16x16x32_bf16(qf[kc], b1, s1, 0, 0, 0);
      }
    }
    // mask (segment compare is complete: sorted seg => equal iff same batch),
    // exp, row-sum partials, P -> LDS (C-layout -> A-layout)
    int sa = seg[j0 + c], sb = seg[j0 + 16 + c];
    short* prow = &Ps[wave][0];
#pragma unroll
    for (int r = 0; r < 4; ++r) {
      float pa = (sa == seg_r[r]) ? __expf(s0[r] * scale) : 0.f;
      float pb = (sb == seg_r[r]) ? __expf(s1[r] * scale) : 0.f;
      l_part[r] += pa + pb;
      int row = quad * 4 + r;
      prow[row * PS_LD + c]      = f2bf(pa);
      prow[row * PS_LD + 16 + c] = f2bf(pb);
    }
    // compiler inserts lgkmcnt wait for the in-wave write->read dependency
    short8 pf = *(const short8*)&Ps[wave][c * PS_LD + quad * 8];
#pragma unroll
    for (int n = 0; n < 8; ++n)
      acc[n] = __builtin_amdgcn_mfma_f32_16x16x32_bf16(pf, vf[n], acc[n], 0, 0, 0);
  }

  // in-wave l reduction over the 16 key-columns
  float lrow[4];
#pragma unroll
  for (int r = 0; r < 4; ++r) {
    float l = l_part[r];
    l += __shfl_xor(l, 1, 64);
    l += __shfl_xor(l, 2, 64);
    l += __shfl_xor(l, 4, 64);
    l += __shfl_xor(l, 8, 64);
    lrow[r] = l;
  }

  // cross-wave reduction of O and l, normalize, store
#pragma unroll
  for (int n = 0; n < 8; ++n)
#pragma unroll
    for (int r = 0; r < 4; ++r)
      Osc[wave][(quad * 4 + r) * DD + n * 16 + c] = acc[n][r];
  if (c == 0) {
#pragma unroll
    for (int r = 0; r < 4; ++r) Ls[wave][quad * 4 + r] = lrow[r];
  }
  __syncthreads();

#pragma unroll
  for (int rep = 0; rep < 2; ++rep) {
    int e4 = rep * 256 + tid;            // [16 rows][32 float4-cols]
    int row = e4 >> 5, c4 = (e4 & 31) * 4;
    float l = Ls[0][row] + Ls[1][row] + Ls[2][row] + Ls[3][row];
    float4v o = (float4v){0.f, 0.f, 0.f, 0.f};
#pragma unroll
    for (int w = 0; w < 4; ++w) {
      float4v t = *(const float4v*)&Osc[w][row * DD + c4];
      o[0] += t[0]; o[1] += t[1]; o[2] += t[2]; o[3] += t[3];
    }
    float inv = 1.f / (l + 1e-8f);
    o[0] *= inv; o[1] *= inv; o[2] *= inv; o[3] *= inv;
    *(float4v*)(out + (size_t)(i0 + row) * DD + c4) = o;
  }
}

// ---------- fallback (verified R1 kernel) if ws_size is too small ----------
#define KT_LD 136
#define VT_LD 40
typedef __attribute__((ext_vector_type(4))) short short4v;

__global__ __launch_bounds__(256) void attn_fallback(
    const float* __restrict__ Q, const float* __restrict__ K,
    const float* __restrict__ V, const int* __restrict__ seg,
    float* __restrict__ out) {
  __shared__ __align__(16) short Kt[32 * KT_LD];
  __shared__ __align__(16) short Vt[DD * VT_LD];
  __shared__ __align__(16) short Ps[4][16 * PS_LD];
  const int tid = threadIdx.x, wave = tid >> 6, lane = tid & 63;
  const int c = lane & 15, quad = lane >> 4;
  const int m0 = blockIdx.x * 64, i0 = m0 + wave * 16;
  const int segFirst = seg[m0], segLast = seg[m0 + 63];
  int lo = 0, hb = NN;
  while (lo < hb) { int mid = (lo + hb) >> 1; if (seg[mid] < segFirst) lo = mid + 1; else hb = mid; }
  int hi = lo, hb2 = NN;
  while (hi < hb2) { int mid = (hi + hb2) >> 1; if (seg[mid] <= segLast) hi = mid + 1; else hb2 = mid; }
  short8 qf[4];
  const float* qrow = Q + (size_t)(i0 + c) * DD + quad * 8;
#pragma unroll
  for (int kc = 0; kc < 4; ++kc) {
    float4v f0 = *(const float4v*)(qrow + kc * 32);
    float4v f1 = *(const float4v*)(qrow + kc * 32 + 4);
    short8 s;
    s[0] = f2bf(f0[0]); s[1] = f2bf(f0[1]); s[2] = f2bf(f0[2]); s[3] = f2bf(f0[3]);
    s[4] = f2bf(f1[0]); s[5] = f2bf(f1[1]); s[6] = f2bf(f1[2]); s[7] = f2bf(f1[3]);
    qf[kc] = s;
  }
  int seg_r[4];
#pragma unroll
  for (int r = 0; r < 4; ++r) seg_r[r] = seg[i0 + quad * 4 + r];
  float4v acc[8];
#pragma unroll
  for (int n = 0; n < 8; ++n) acc[n] = (float4v){0.f, 0.f, 0.f, 0.f};
  float l_part[4] = {0.f, 0.f, 0.f, 0.f};
  const float scale = 0.08838834764831845f;
  for (int j0 = lo; j0 < hi; j0 += 32) {
    __syncthreads();
    {
      int row = tid >> 3, ch = tid & 7;
      int jj = j0 + row; if (jj > NN - 1) jj = NN - 1;
      const float* kp = K + (size_t)jj * DD + ch * 16;
      short* dst = &Kt[row * KT_LD + ch * 16];
#pragma unroll
      for (int q4 = 0; q4 < 4; ++q4) {
        float4v f = *(const float4v*)(kp + q4 * 4);
        short4v s;
        s[0] = f2bf(f[0]); s[1] = f2bf(f[1]); s[2] = f2bf(f[2]); s[3] = f2bf(f[3]);
        *(short4v*)(dst + q4 * 4) = s;
      }
    }
    {
      int d = tid & 127, jh = tid >> 7;
      float vv[16];
#pragma unroll
      for (int j = 0; j < 16; ++j) {
        int jj = j0 + jh * 16 + j; if (jj > NN - 1) jj = NN - 1;
        vv[j] = V[(size_t)jj * DD + d];
      }
      short8 a, b2;
#pragma unroll
      for (int j = 0; j < 8; ++j) { a[j] = f2bf(vv[j]); b2[j] = f2bf(vv[8 + j]); }
      *(short8*)&Vt[d * VT_LD + jh * 16] = a;
      *(short8*)&Vt[d * VT_LD + jh * 16 + 8] = b2;
    }
    __syncthreads();
    float4v s0 = (float4v){0.f, 0.f, 0.f, 0.f};
    float4v s1 = (float4v){0.f, 0.f, 0.f, 0.f};
    const short* krow0 = &Kt[c * KT_LD + quad * 8];
    const short* krow1 = &Kt[(16 + c) * KT_LD + quad * 8];
#pragma unroll
    for (int kc = 0; kc < 4; ++kc) {
      short8 b0 = *(const short8*)(krow0 + kc * 32);
      short8 b1 = *(const short8*)(krow1 + kc * 32);
      s0 = __builtin_amdgcn_mfma_f32_16x16x32_bf16(qf[kc], b0, s0, 0, 0, 0);
      s1 = __builtin_amdgcn_mfma_f32_16x16x32_bf16(qf[kc], b1, s1, 0, 0, 0);
    }
    int ja = j0 + c, jb = ja + 16;
    int sa = seg[ja < NN ? ja : NN - 1];
    int sb = seg[jb < NN ? jb : NN - 1];
    bool va = ja < hi, vb = jb < hi;
    short* prow = &Ps[wave][0];
#pragma unroll
    for (int r = 0; r < 4; ++r) {
      float pa = (va && sa == seg_r[r]) ? __expf(s0[r] * scale) : 0.f;
      float pb = (vb && sb == seg_r[r]) ? __expf(s1[r] * scale) : 0.f;
      l_part[r] += pa + pb;
      int row = quad * 4 + r;
      prow[row * PS_LD + c] = f2bf(pa);
      prow[row * PS_LD + 16 + c] = f2bf(pb);
    }
    short8 pf = *(const short8*)&Ps[wave][c * PS_LD + quad * 8];
#pragma unroll
    for (int n = 0; n < 8; ++n) {
      short8 vfr = *(const short8*)&Vt[(n * 16 + c) * VT_LD + quad * 8];
      acc[n] = __builtin_amdgcn_mfma_f32_16x16x32_bf16(pf, vfr, acc[n], 0, 0, 0);
    }
  }
  float linv[4];
#pragma unroll
  for (int r = 0; r < 4; ++r) {
    float l = l_part[r];
    l += __shfl_xor(l, 1, 64);
    l += __shfl_xor(l, 2, 64);
    l += __shfl_xor(l, 4, 64);
    l += __shfl_xor(l, 8, 64);
    linv[r] = 1.f / (l + 1e-8f);
  }
#pragma unroll
  for (int n = 0; n < 8; ++n)
#pragma unroll
    for (int r = 0; r < 4; ++r)
      out[(size_t)(i0 + quad * 4 + r) * DD + n * 16 + c] = acc[n][r] * linv[r];
}

extern "C" void kernel_launch(void* const* d_in, const int* in_sizes, int n_in,
                              void* d_out, int out_size, void* d_ws, size_t ws_size,
                              hipStream_t stream) {
  const float* Q = (const float*)d_in[0];
  const float* K = (const float*)d_in[1];
  const float* V = (const float*)d_in[2];
  const int* seg = (const int*)d_in[4];
  float* out = (float*)d_out;

  const size_t kb_bytes = (size_t)NN * DD * sizeof(short);   // 3145728
  const size_t vt_bytes = (size_t)DD * NN * sizeof(short);   // 3145728
  const size_t need = kb_bytes + vt_bytes + 64 * sizeof(int);

  if (ws_size >= need) {
    short* Kb  = (short*)d_ws;
    short* Vtb = (short*)((char*)d_ws + kb_bytes);
    int* starts = (int*)((char*)d_ws + kb_bytes + vt_bytes);
    prep_kernel<<<865, 256, 0, stream>>>(K, V, seg, Kb, Vtb, starts);
    attn_kernel<<<NN / 16, 256, 0, stream>>>(Q, Kb, Vtb, seg, starts, out);
  } else {
    attn_fallback<<<NN / 64, 256, 0, stream>>>(Q, K, V, seg, out);
  }
}